// Round 9
// baseline (204.319 us; speedup 1.0000x reference)
//
#include <hip/hip_runtime.h>
#include <cstddef>

#define NN 1024
#define CL 384
#define CP 128
#define NH 8
#define KS 32
#define HK 256

typedef float floatx4 __attribute__((ext_vector_type(4)));

template<int CTRL>
__device__ __forceinline__ float dpp_mov(float v) {
    return __int_as_float(__builtin_amdgcn_update_dpp(
        0, __float_as_int(v), CTRL, 0xF, 0xF, true));
}

__device__ __forceinline__ float4 ntload4(const float* p) {
    floatx4 t = __builtin_nontemporal_load((const floatx4*)p);
    float4 r; r.x = t.x; r.y = t.y; r.z = t.z; r.w = t.w;
    return r;
}

// ---------------- Kernel 1: LayerNorm + value projection ----------------
// value[r][m], m = h*32+c  (row-major, m contiguous)
__global__ __launch_bounds__(256) void k_ln_value(
    const float* __restrict__ local_, const float* __restrict__ ln_scale,
    const float* __restrict__ ln_offset, const float* __restrict__ Wv,
    float* __restrict__ value)
{
    __shared__ float ln_s[4][CL];
    const int tid = threadIdx.x;
    const int w = tid >> 6, lane = tid & 63;
    const int r = blockIdx.x * 4 + w;
    const float* lp = local_ + (size_t)r * CL;
    float x[6]; float s1 = 0.f, s2 = 0.f;
#pragma unroll
    for (int k = 0; k < 6; ++k) { x[k] = lp[lane + 64*k]; s1 += x[k]; s2 += x[k]*x[k]; }
#pragma unroll
    for (int m = 1; m < 64; m <<= 1) { s1 += __shfl_xor(s1, m); s2 += __shfl_xor(s2, m); }
    const float mean = s1 * (1.f/CL);
    const float var  = fmaxf(s2 * (1.f/CL) - mean*mean, 0.f);
    const float rstd = rsqrtf(var + 1e-5f);
#pragma unroll
    for (int k = 0; k < 6; ++k) {
        const int c = lane + 64*k;
        ln_s[w][c] = (x[k]-mean)*rstd*ln_scale[c] + ln_offset[c];
    }
    __syncthreads();
    const int m_ = tid;
    float acc0=0.f, acc1=0.f, acc2=0.f, acc3=0.f;
    for (int c0 = 0; c0 < CL; c0 += 8) {
        float wv[8];
#pragma unroll
        for (int cc = 0; cc < 8; ++cc) wv[cc] = Wv[(size_t)(c0+cc)*HK + m_];
        {
            const float4 a = *(const float4*)&ln_s[0][c0];
            const float4 b = *(const float4*)&ln_s[0][c0+4];
            acc0 += a.x*wv[0]+a.y*wv[1]+a.z*wv[2]+a.w*wv[3]+b.x*wv[4]+b.y*wv[5]+b.z*wv[6]+b.w*wv[7];
        }
        {
            const float4 a = *(const float4*)&ln_s[1][c0];
            const float4 b = *(const float4*)&ln_s[1][c0+4];
            acc1 += a.x*wv[0]+a.y*wv[1]+a.z*wv[2]+a.w*wv[3]+b.x*wv[4]+b.y*wv[5]+b.z*wv[6]+b.w*wv[7];
        }
        {
            const float4 a = *(const float4*)&ln_s[2][c0];
            const float4 b = *(const float4*)&ln_s[2][c0+4];
            acc2 += a.x*wv[0]+a.y*wv[1]+a.z*wv[2]+a.w*wv[3]+b.x*wv[4]+b.y*wv[5]+b.z*wv[6]+b.w*wv[7];
        }
        {
            const float4 a = *(const float4*)&ln_s[3][c0];
            const float4 b = *(const float4*)&ln_s[3][c0+4];
            acc3 += a.x*wv[0]+a.y*wv[1]+a.z*wv[2]+a.w*wv[3]+b.x*wv[4]+b.y*wv[5]+b.z*wv[6]+b.w*wv[7];
        }
    }
    const int rb = blockIdx.x*4;
    value[(size_t)(rb+0)*HK + m_] = acc0;
    value[(size_t)(rb+1)*HK + m_] = acc1;
    value[(size_t)(rb+2)*HK + m_] = acc2;
    value[(size_t)(rb+3)*HK + m_] = acc3;
}

// ---------------- Kernel 2: fused attention, wave-local, queue-ordered ------
// Per iteration (8 j-rows): (1) value loads FIRST (oldest in vmem queue),
// (2) logits consume pair buffer loaded 2 iterations ago (already retired),
// (3) pair prefetch for t+2 (youngest, 2 iterations of latency cover),
// (4) p-broadcast + PV from value regs (vmcnt wait leaves prefetch in flight).
// No barriers in the loop; cross-wave combine once in the epilogue.
__global__ __launch_bounds__(256, 4) void k_attn(
    const float* __restrict__ pair, const int* __restrict__ mask,
    const float* __restrict__ Wa, const float* __restrict__ value,
    const float* __restrict__ Wo, float* __restrict__ outp)
{
    __shared__ float zf[NN];            // mask factor per j
    __shared__ float sep[4][NH];        // per-wave denominators
    __shared__ float ov4[4][64][4];     // per-wave PV partials
    __shared__ float ov[HK];            // normalized attention vector

    const int tid  = threadIdx.x;
    const int w    = tid >> 6;          // wave 0..3
    const int lane = tid & 63;
    const int sub5 = lane & 31;
    const int half = lane >> 5;         // row parity within 2-row group
    const int i = blockIdx.x;
    const bool bmi = mask[i] != 0;

    for (int k = tid; k < NN; k += 256)
        zf[k] = (bmi && (mask[k] != 0)) ? 1.f : 0.f;

    // W_attn rows sub5*4 .. +3, all 8 heads; wreg[cc*8+h]
    float wreg[32];
    {
        const float4* wp = (const float4*)(Wa + sub5*4*NH);
#pragma unroll
        for (int k = 0; k < 8; ++k) {
            const float4 t4 = wp[k];
            wreg[4*k+0]=t4.x; wreg[4*k+1]=t4.y; wreg[4*k+2]=t4.z; wreg[4*k+3]=t4.w;
        }
    }

    // PV head of this lane (owns m = lane*4..+3) and broadcast source lanes
    const int hpv  = lane >> 3;
    const int srcE = ((hpv>>2)&1) + 2*((hpv>>1)&1) + 8*(hpv&1);  // owner, lower half
    const int srcO = srcE + 32;

    const int jbase = w * 256;
    const float* pb = pair + (size_t)i*NN*CP + sub5*4;

    float4 ac4; ac4.x = ac4.y = ac4.z = ac4.w = 0.f;
    float se_loc = 0.f;

    float4 pA[4], pB[4];
#pragma unroll
    for (int s = 0; s < 4; ++s)
        pA[s] = ntload4(pb + (size_t)(jbase + 2*s + half)*CP);
#pragma unroll
    for (int s = 0; s < 4; ++s)
        pB[s] = ntload4(pb + (size_t)(jbase + 8 + 2*s + half)*CP);

    __syncthreads();        // zf ready (prologue only)

#define ITER(BUF, T)                                                          \
    {                                                                         \
        const int j0 = jbase + (T)*8;                                         \
        const int jp = jbase + ((((T)+2)&31)*8);                              \
        /* 1. value loads first (oldest) */                                   \
        float4 ve[4], vo[4];                                                  \
        {                                                                     \
            const float* vb0 = value + (size_t)j0*HK + lane*4;                \
            _Pragma("unroll")                                                 \
            for (int s = 0; s < 4; ++s) {                                     \
                ve[s] = *(const float4*)(vb0 + (size_t)(2*s)*HK);             \
                vo[s] = *(const float4*)(vb0 + (size_t)(2*s+1)*HK);           \
            }                                                                 \
        }                                                                     \
        /* 2. logits consume BUF (retired long ago) */                        \
        float pe[4];                                                          \
        _Pragma("unroll")                                                     \
        for (int s = 0; s < 4; ++s) {                                         \
            const float4 c = BUF[s];                                          \
            float acc[8];                                                     \
            _Pragma("unroll")                                                 \
            for (int h = 0; h < 8; ++h)                                       \
                acc[h] = c.x*wreg[h] + c.y*wreg[8+h]                          \
                       + c.z*wreg[16+h] + c.w*wreg[24+h];                     \
            const bool b0 = (sub5 & 1) != 0;                                  \
            const bool b1 = (sub5 & 2) != 0;                                  \
            const bool b3 = (sub5 & 8) != 0;                                  \
            float r4[4];                                                      \
            _Pragma("unroll")                                                 \
            for (int k = 0; k < 4; ++k)                                       \
                r4[k] = (b0 ? acc[k+4] : acc[k])                              \
                      + dpp_mov<0xB1>(b0 ? acc[k] : acc[k+4]);                \
            float r2[2];                                                      \
            _Pragma("unroll")                                                 \
            for (int k = 0; k < 2; ++k)                                       \
                r2[k] = (b1 ? r4[k+2] : r4[k])                                \
                      + dpp_mov<0x4E>(b1 ? r4[k] : r4[k+2]);                  \
            float r1 = (b3 ? r2[1] : r2[0])                                   \
                     + dpp_mov<0x128>(b3 ? r2[0] : r2[1]);                    \
            r1 += __shfl_xor(r1, 4);                                          \
            r1 += __shfl_xor(r1, 16);                                         \
            pe[s] = __expf(r1);                                               \
        }                                                                     \
        /* 3. pair prefetch for T+2 (youngest; long cover) */                 \
        _Pragma("unroll")                                                     \
        for (int s = 0; s < 4; ++s)                                           \
            BUF[s] = ntload4(pb + (size_t)(jp + 2*s + half)*CP);              \
        /* 4. broadcast + PV (waits only on value loads) */                   \
        _Pragma("unroll")                                                     \
        for (int s = 0; s < 4; ++s) {                                         \
            const float p_e = __shfl(pe[s], srcE) * zf[j0 + 2*s];             \
            const float p_o = __shfl(pe[s], srcO) * zf[j0 + 2*s + 1];         \
            se_loc += p_e + p_o;                                              \
            ac4.x += p_e*ve[s].x + p_o*vo[s].x;                               \
            ac4.y += p_e*ve[s].y + p_o*vo[s].y;                               \
            ac4.z += p_e*ve[s].z + p_o*vo[s].z;                               \
            ac4.w += p_e*ve[s].w + p_o*vo[s].w;                               \
        }                                                                     \
    }

    for (int t = 0; t < 32; t += 2) {
        ITER(pA, t);
        ITER(pB, t+1);
    }
#undef ITER

    // ---- epilogue: combine 4 waves ----
    if ((lane & 7) == 0) sep[w][hpv] = se_loc;    // 8 identical lanes per h
    ov4[w][lane][0] = ac4.x; ov4[w][lane][1] = ac4.y;
    ov4[w][lane][2] = ac4.z; ov4[w][lane][3] = ac4.w;
    __syncthreads();

    {   // combine, normalize
        const int m = tid;               // 0..255
        const float s4 = ov4[0][m>>2][m&3] + ov4[1][m>>2][m&3]
                       + ov4[2][m>>2][m&3] + ov4[3][m>>2][m&3];
        const int h = m >> 5;
        const float se = sep[0][h] + sep[1][h] + sep[2][h] + sep[3][h];
        const float inv = (se > 0.f) ? (1.f/se) : 0.f;
        ov[m] = s4 * inv;
    }
    __syncthreads();

    // ---- final projection out = ov @ W_out ----
    for (int o = tid; o < CL; o += 256) {
        float a0 = 0.f;
        for (int m = 0; m < HK; m += 4) {
            const float4 x0 = *(const float4*)&ov[m];
            a0 += x0.x*Wo[(size_t)(m+0)*CL + o] + x0.y*Wo[(size_t)(m+1)*CL + o]
                + x0.z*Wo[(size_t)(m+2)*CL + o] + x0.w*Wo[(size_t)(m+3)*CL + o];
        }
        outp[(size_t)i*CL + o] = a0;
    }
}

extern "C" void kernel_launch(void* const* d_in, const int* in_sizes, int n_in,
                              void* d_out, int out_size, void* d_ws, size_t ws_size,
                              hipStream_t stream)
{
    (void)in_sizes; (void)n_in; (void)out_size; (void)ws_size;
    const float* local_ = (const float*)d_in[0];
    const float* pair   = (const float*)d_in[1];
    const int*   mask   = (const int*)d_in[2];
    const float* scale  = (const float*)d_in[3];
    const float* offset = (const float*)d_in[4];
    const float* Wv     = (const float*)d_in[5];
    const float* Wa     = (const float*)d_in[6];
    const float* Wo     = (const float*)d_in[7];
    float* value = (float*)d_ws;          // 1 MiB scratch: [1024][256]
    k_ln_value<<<NN/4, 256, 0, stream>>>(local_, scale, offset, Wv, value);
    k_attn<<<NN, 256, 0, stream>>>(pair, mask, Wa, value, Wo, (float*)d_out);
}